// Round 7
// baseline (482.065 us; speedup 1.0000x reference)
//
#include <hip/hip_runtime.h>
#include <hip/hip_bf16.h>

#define CC 192

typedef __attribute__((ext_vector_type(8))) short bf16x8;
typedef __attribute__((ext_vector_type(4))) float f32x4;

__device__ __forceinline__ unsigned short f2bf(float f) {
    unsigned int u = __float_as_uint(f);
    u = (u + 0x7fffu + ((u >> 16) & 1u)) >> 16;
    return (unsigned short)u;
}

__device__ __forceinline__ f32x4 mfma16(bf16x8 a, bf16x8 b, f32x4 c) {
    return __builtin_amdgcn_mfma_f32_16x16x32_bf16(a, b, c, 0, 0, 0);
}

// Merged prep: 4 weight transposes (f32 [K][N] -> bf16 [N][K]) + bias expand.
__global__ void k_prep(const float* __restrict__ qkv_w, const float* __restrict__ proj_w,
                       const float* __restrict__ w1, const float* __restrict__ w2,
                       const float* __restrict__ relTab,
                       unsigned short* __restrict__ qkvT, unsigned short* __restrict__ projT,
                       unsigned short* __restrict__ w1T, unsigned short* __restrict__ w2T,
                       float* __restrict__ biasT) {
    int idx = blockIdx.x * blockDim.x + threadIdx.x;
    if (idx < 110592) { int n = idx / 192, k = idx % 192; qkvT[idx] = f2bf(qkv_w[k * 576 + n]); return; }
    idx -= 110592;
    if (idx < 36864)  { int n = idx / 192, k = idx % 192; projT[idx] = f2bf(proj_w[k * 192 + n]); return; }
    idx -= 36864;
    if (idx < 73728)  { int n = idx / 192, k = idx % 192; w1T[idx] = f2bf(w1[k * 384 + n]); return; }
    idx -= 73728;
    if (idx < 73728)  { int n = idx / 384, k = idx % 384; w2T[idx] = f2bf(w2[k * 192 + n]); return; }
    idx -= 73728;
    if (idx < 24576) {
        int h = idx >> 12, i = (idx >> 6) & 63, j = idx & 63;
        int yi = i >> 3, xi = i & 7, yj = j >> 3, xj = j & 7;
        int rel = (yi - yj + 7) * 15 + (xi - xj + 7);
        biasT[idx] = relTab[rel * 6 + h];
    }
}

// One window per block (2048 blocks), 6 waves, ONE HEAD PER WAVE end-to-end.
// LDS (49.4 KB -> 2 blocks/CU):
//   X [24576 B]: A (swz [64][192] bf16) --bar2--> per-wave P-half slots (4 KB) --bar3--> AO (swz [64][192])
//   Y [24576 B]: per-wave 4 KB slot cycling Q (swz [64][32]) -> K -> VT-half (swz [32][32]) x2
// Attention (Q/K frag loads, QK^T, softmax, PV) is fully wave-private: NO barriers.
__global__ __launch_bounds__(384, 3) void k_attn(
    const float* __restrict__ x,
    const float* __restrict__ n1g, const float* __restrict__ n1b,
    const unsigned short* __restrict__ qkvT, const float* __restrict__ qkv_b,
    const unsigned short* __restrict__ projT, const float* __restrict__ proj_b,
    const float* __restrict__ biasTab,
    float* __restrict__ out)
{
    __shared__ __align__(16) char smem[49152];
    __shared__ int sOpos[64];
    char* const X = smem;
    char* const Y = smem + 24576;

    const int tid = threadIdx.x;
    const int wid = blockIdx.x;
    const int b = wid >> 6;
    const int win = wid & 63;
    const int wh = win >> 3, ww = win & 7;
    const int lane = tid & 63;
    const int wave = tid >> 6;
    const int lhi = lane >> 4, llo = lane & 15;

    // ---------- Phase 1: LN1 + shifted window gather (256 threads, 4/token) ----------
    if (tid < 256) {
        const int tok = tid >> 2;
        const int ch0 = (tid & 3) * 48;
        const int yi = tok >> 3, xi = tok & 7;
        const int oy = (wh * 8 + yi + 4) & 63;
        const int ox = (ww * 8 + xi + 4) & 63;
        const int base = ((b * 64 + oy) * 64 + ox) * CC;
        if ((tid & 3) == 0) sOpos[tok] = base;
        float v[48];
        float s = 0.f, ss = 0.f;
        #pragma unroll
        for (int i = 0; i < 12; ++i) {
            const float4 f = *(const float4*)(x + base + ch0 + i * 4);
            v[i*4+0]=f.x; v[i*4+1]=f.y; v[i*4+2]=f.z; v[i*4+3]=f.w;
            s  += f.x + f.y + f.z + f.w;
            ss += f.x*f.x + f.y*f.y + f.z*f.z + f.w*f.w;
        }
        s  += __shfl_xor(s, 1);  s  += __shfl_xor(s, 2);
        ss += __shfl_xor(ss, 1); ss += __shfl_xor(ss, 2);
        const float mean = s * (1.f / 192.f);
        const float rstd = rsqrtf(ss * (1.f / 192.f) - mean * mean + 1e-5f);
        char* aBase = X + tok * 384;
        const int sw = (tok & 7) << 4;
        #pragma unroll
        for (int i = 0; i < 24; ++i) {
            const int c = ch0 + i * 2;
            const float a0 = (v[i*2+0] - mean) * rstd * n1g[c]   + n1b[c];
            const float a1 = (v[i*2+1] - mean) * rstd * n1g[c+1] + n1b[c+1];
            *(unsigned int*)(aBase + ((c * 2) ^ sw)) =
                (unsigned int)f2bf(a0) | ((unsigned int)f2bf(a1) << 16);
        }
    }
    __syncthreads();   // bar1: A ready

    const int h = wave;
    char* const slotY = Y + h * 4096;   // Q -> K -> VT-half cycle
    char* const slotP = X + h * 4096;   // P-half slot (valid after bar2)

    // ---------- Phase 2: QKV GEMM for this head: cols q|k|v of head h (acc[4][6]) ----------
    f32x4 acc[4][6] = {};
    #pragma unroll
    for (int ks = 0; ks < 6; ++ks) {
        bf16x8 af[4];
        const int kbyte = ks * 64 + lhi * 16;
        #pragma unroll
        for (int m = 0; m < 4; ++m) {
            const int row = m * 16 + llo;
            af[m] = *(const bf16x8*)(X + row * 384 + (kbyte ^ ((row & 7) << 4)));
        }
        #pragma unroll
        for (int n = 0; n < 6; ++n) {
            const int col = (n >> 1) * 192 + h * 32 + (n & 1) * 16 + llo;
            const bf16x8 bfr = *(const bf16x8*)(qkvT + col * 192 + ks * 32 + lhi * 8);
            #pragma unroll
            for (int m = 0; m < 4; ++m) acc[m][n] = mfma16(af[m], bfr, acc[m][n]);
        }
    }
    __syncthreads();   // bar2: A consumed by ALL waves; X reusable (P slots / AO later)

    // ---------- wave-private attention (no barriers until bar3) ----------
    // scatter Q (xSCALE +bias) -> slotY
    #pragma unroll
    for (int n = 0; n < 2; ++n) {
        const int d = n * 16 + llo;
        const float bia = qkv_b[h * 32 + d];
        #pragma unroll
        for (int m = 0; m < 4; ++m) {
            #pragma unroll
            for (int r = 0; r < 4; ++r) {
                const int row = m * 16 + lhi * 4 + r;
                *(unsigned short*)(slotY + row * 64 + ((2 * d) ^ ((row & 3) << 4)))
                    = f2bf((acc[m][n][r] + bia) * 0.17677669529663687f);
            }
        }
    }
    bf16x8 qf[4];
    #pragma unroll
    for (int m = 0; m < 4; ++m) {
        const int t = m * 16 + llo;
        qf[m] = *(const bf16x8*)(slotY + t * 64 + ((lhi * 16) ^ ((t & 3) << 4)));
    }
    // scatter K -> slotY (overwrites Q; qf already in regs, same-wave ordering)
    #pragma unroll
    for (int n = 0; n < 2; ++n) {
        const int d = n * 16 + llo;
        const float bia = qkv_b[192 + h * 32 + d];
        #pragma unroll
        for (int m = 0; m < 4; ++m) {
            #pragma unroll
            for (int r = 0; r < 4; ++r) {
                const int row = m * 16 + lhi * 4 + r;
                *(unsigned short*)(slotY + row * 64 + ((2 * d) ^ ((row & 3) << 4)))
                    = f2bf(acc[m][n + 2][r] + bia);
            }
        }
    }
    bf16x8 kf[4];
    #pragma unroll
    for (int m = 0; m < 4; ++m) {
        const int t = m * 16 + llo;
        kf[m] = *(const bf16x8*)(slotY + t * 64 + ((lhi * 16) ^ ((t & 3) << 4)));
    }
    const float biaV0 = qkv_b[384 + h * 32 + llo];
    const float biaV1 = qkv_b[384 + h * 32 + 16 + llo];
    // scatter VT-half0 (V rows 0..31 = acc m=0,1) -> slotY[0,2048)
    #pragma unroll
    for (int n = 0; n < 2; ++n) {
        const int d = n * 16 + llo;
        const float bia = n ? biaV1 : biaV0;
        #pragma unroll
        for (int m = 0; m < 2; ++m) {
            #pragma unroll
            for (int r = 0; r < 4; ++r) {
                const int kk = m * 16 + lhi * 4 + r;
                *(unsigned short*)(slotY + d * 64 + ((2 * kk) ^ ((d & 3) << 4)))
                    = f2bf(acc[m][n + 4][r] + bia);
            }
        }
    }

    // QK^T (full head: 64x64 scores per wave)
    f32x4 sacc[4][4] = {};
    #pragma unroll
    for (int m = 0; m < 4; ++m)
        #pragma unroll
        for (int n = 0; n < 4; ++n)
            sacc[m][n] = mfma16(qf[m], kf[n], sacc[m][n]);

    // softmax (no-max: scores O(1), f32-exp safe) -> P-half0 to slotP, half1 kept packed
    const bool eH = (wh == 7), eW = (ww == 7);
    int idj[4];
    #pragma unroll
    for (int n = 0; n < 4; ++n) {
        const int j = n * 16 + llo;
        idj[n] = (eH ? ((j >> 3) >= 4 ? 2 : 1) : 0) * 3 + (eW ? ((j & 7) >= 4 ? 2 : 1) : 0);
    }
    const float* bT = biasTab + h * 4096;
    unsigned pb1[4][4];
    float rinv[4][4];
    #pragma unroll
    for (int m = 0; m < 4; ++m) {
        #pragma unroll
        for (int r = 0; r < 4; ++r) {
            const int i = m * 16 + lhi * 4 + r;
            const int idi = (eH ? ((i >> 3) >= 4 ? 2 : 1) : 0) * 3 +
                            (eW ? ((i & 7) >= 4 ? 2 : 1) : 0);
            float sum = 0.f;
            unsigned short pb[4];
            #pragma unroll
            for (int n = 0; n < 4; ++n) {
                const int j = n * 16 + llo;
                float e = __expf(sacc[m][n][r] + bT[i * 64 + j]);
                if (idi != idj[n]) e = 0.f;
                sum += e;
                pb[n] = f2bf(e);
            }
            sum += __shfl_xor(sum, 1);
            sum += __shfl_xor(sum, 2);
            sum += __shfl_xor(sum, 4);
            sum += __shfl_xor(sum, 8);
            rinv[m][r] = 1.f / sum;
            const int sw = (i & 3) << 4;
            *(unsigned short*)(slotP + i * 64 + ((2 * llo) ^ sw)) = pb[0];
            *(unsigned short*)(slotP + i * 64 + ((2 * (16 + llo)) ^ sw)) = pb[1];
            pb1[m][r] = (unsigned)pb[2] | ((unsigned)pb[3] << 16);
        }
    }

    // PV half0: P[:,0:32] x V[0:32,:]
    f32x4 pacc[4][2] = {};
    {
        bf16x8 pf[4];
        #pragma unroll
        for (int m = 0; m < 4; ++m) {
            const int t = m * 16 + llo;
            pf[m] = *(const bf16x8*)(slotP + t * 64 + ((lhi * 16) ^ ((t & 3) << 4)));
        }
        #pragma unroll
        for (int n = 0; n < 2; ++n) {
            const int d = n * 16 + llo;
            const bf16x8 vf = *(const bf16x8*)(slotY + d * 64 + ((lhi * 16) ^ ((d & 3) << 4)));
            #pragma unroll
            for (int m = 0; m < 4; ++m) pacc[m][n] = mfma16(pf[m], vf, pacc[m][n]);
        }
    }
    // scatter VT-half1 (V rows 32..63 = acc m=2,3), overwrite slotY
    #pragma unroll
    for (int n = 0; n < 2; ++n) {
        const int d = n * 16 + llo;
        const float bia = n ? biaV1 : biaV0;
        #pragma unroll
        for (int m = 0; m < 2; ++m) {
            #pragma unroll
            for (int r = 0; r < 4; ++r) {
                const int kk = m * 16 + lhi * 4 + r;
                *(unsigned short*)(slotY + d * 64 + ((2 * kk) ^ ((d & 3) << 4)))
                    = f2bf(acc[m + 2][n + 4][r] + bia);
            }
        }
    }
    // write P-half1, overwrite slotP
    #pragma unroll
    for (int m = 0; m < 4; ++m) {
        #pragma unroll
        for (int r = 0; r < 4; ++r) {
            const int i = m * 16 + lhi * 4 + r;
            const int sw = (i & 3) << 4;
            const unsigned u = pb1[m][r];
            *(unsigned short*)(slotP + i * 64 + ((2 * llo) ^ sw)) = (unsigned short)u;
            *(unsigned short*)(slotP + i * 64 + ((2 * (16 + llo)) ^ sw)) = (unsigned short)(u >> 16);
        }
    }
    // PV half1
    {
        bf16x8 pf[4];
        #pragma unroll
        for (int m = 0; m < 4; ++m) {
            const int t = m * 16 + llo;
            pf[m] = *(const bf16x8*)(slotP + t * 64 + ((lhi * 16) ^ ((t & 3) << 4)));
        }
        #pragma unroll
        for (int n = 0; n < 2; ++n) {
            const int d = n * 16 + llo;
            const bf16x8 vf = *(const bf16x8*)(slotY + d * 64 + ((lhi * 16) ^ ((d & 3) << 4)));
            #pragma unroll
            for (int m = 0; m < 4; ++m) pacc[m][n] = mfma16(pf[m], vf, pacc[m][n]);
        }
    }
    __syncthreads();   // bar3: all waves' P/VT traffic done; X free for AO

    // AO -> X (swz [64][192])
    #pragma unroll
    for (int m = 0; m < 4; ++m) {
        #pragma unroll
        for (int n = 0; n < 2; ++n) {
            const int c = h * 32 + n * 16 + llo;
            #pragma unroll
            for (int r = 0; r < 4; ++r) {
                const int i = m * 16 + lhi * 4 + r;
                *(unsigned short*)(X + i * 384 + ((c * 2) ^ ((i & 7) << 4)))
                    = f2bf(pacc[m][n][r] * rinv[m][r]);
            }
        }
    }
    __syncthreads();   // bar4: AO ready

    // ---------- Phase 4: proj GEMM + residual, wave -> cols [32h, 32h+32) ----------
    {
        f32x4 accP[4][2] = {};
        #pragma unroll
        for (int ks = 0; ks < 6; ++ks) {
            bf16x8 af[4];
            const int kbyte = ks * 64 + lhi * 16;
            #pragma unroll
            for (int m = 0; m < 4; ++m) {
                const int row = m * 16 + llo;
                af[m] = *(const bf16x8*)(X + row * 384 + (kbyte ^ ((row & 7) << 4)));
            }
            #pragma unroll
            for (int n = 0; n < 2; ++n) {
                const int col = h * 32 + n * 16 + llo;
                const bf16x8 bfr = *(const bf16x8*)(projT + col * 192 + ks * 32 + lhi * 8);
                #pragma unroll
                for (int m = 0; m < 4; ++m) accP[m][n] = mfma16(af[m], bfr, accP[m][n]);
            }
        }
        #pragma unroll
        for (int n = 0; n < 2; ++n) {
            const int c = h * 32 + n * 16 + llo;
            const float pb = proj_b[c];
            #pragma unroll
            for (int m = 0; m < 4; ++m) {
                #pragma unroll
                for (int r = 0; r < 4; ++r) {
                    const int i = m * 16 + lhi * 4 + r;
                    const int base = sOpos[i];
                    out[base + c] = x[base + c] + accP[m][n][r] + pb;
                }
            }
        }
    }
}

// 64 tokens per block, 8 waves (2 waves per row-half group). In-place on io.
// LDS: one 48 KiB region: A (swz [64][192], first 24 KiB) -> G (swz [64][384], all 48 KiB).
__global__ __launch_bounds__(512, 4) void k_mlp(
    const float* __restrict__ n2g, const float* __restrict__ n2b,
    const unsigned short* __restrict__ w1T, const float* __restrict__ b1,
    const unsigned short* __restrict__ w2T, const float* __restrict__ b2,
    float* __restrict__ io)
{
    __shared__ __align__(16) char smem[49152];
    const int tid = threadIdx.x;
    const int lane = tid & 63, wave = tid >> 6;
    const int lhi = lane >> 4, llo = lane & 15;
    const int mh = wave & 1;
    const long t0 = (long)blockIdx.x * 64;

    {
        const int tok = tid >> 3;
        const int ch0 = (tid & 7) * 24;
        const float* hp = io + (t0 + tok) * CC;
        float v[24]; float s = 0.f, ss = 0.f;
        #pragma unroll
        for (int i = 0; i < 6; ++i) {
            const float4 f = *(const float4*)(hp + ch0 + i * 4);
            v[i*4]=f.x; v[i*4+1]=f.y; v[i*4+2]=f.z; v[i*4+3]=f.w;
            s += f.x + f.y + f.z + f.w;
            ss += f.x*f.x + f.y*f.y + f.z*f.z + f.w*f.w;
        }
        s  += __shfl_xor(s, 1);  s  += __shfl_xor(s, 2);  s  += __shfl_xor(s, 4);
        ss += __shfl_xor(ss, 1); ss += __shfl_xor(ss, 2); ss += __shfl_xor(ss, 4);
        const float mean = s * (1.f / 192.f);
        const float rstd = rsqrtf(ss * (1.f / 192.f) - mean * mean + 1e-5f);
        char* aBase = smem + tok * 384;
        const int sw = (tok & 7) << 4;
        #pragma unroll
        for (int i = 0; i < 12; ++i) {
            const int c = ch0 + i * 2;
            const float a0 = (v[i*2]   - mean) * rstd * n2g[c]   + n2b[c];
            const float a1 = (v[i*2+1] - mean) * rstd * n2g[c+1] + n2b[c+1];
            *(unsigned int*)(aBase + ((c * 2) ^ sw)) =
                (unsigned int)f2bf(a0) | ((unsigned int)f2bf(a1) << 16);
        }
    }
    __syncthreads();
    // GEMM1 (192 -> 384) + exact GELU: wave -> rows [32mh,32mh+32) x cols [(w>>1)*96, +96)
    {
        const int cbase = (wave >> 1) * 96;
        f32x4 acc[2][6] = {};
        #pragma unroll
        for (int ks = 0; ks < 6; ++ks) {
            bf16x8 af[2];
            const int kbyte = ks * 64 + lhi * 16;
            #pragma unroll
            for (int m = 0; m < 2; ++m) {
                const int row = (mh * 2 + m) * 16 + llo;
                af[m] = *(const bf16x8*)(smem + row * 384 + (kbyte ^ ((row & 7) << 4)));
            }
            #pragma unroll
            for (int n = 0; n < 6; ++n) {
                const int col = cbase + n * 16 + llo;
                const bf16x8 bfr = *(const bf16x8*)(w1T + col * 192 + ks * 32 + lhi * 8);
                #pragma unroll
                for (int m = 0; m < 2; ++m) acc[m][n] = mfma16(af[m], bfr, acc[m][n]);
            }
        }
        __syncthreads();   // A consumed; region free for G
        #pragma unroll
        for (int n = 0; n < 6; ++n) {
            const int c = cbase + n * 16 + llo;
            const float bb = b1[c];
            #pragma unroll
            for (int m = 0; m < 2; ++m) {
                #pragma unroll
                for (int r = 0; r < 4; ++r) {
                    const int i = (mh * 2 + m) * 16 + lhi * 4 + r;
                    const float u = acc[m][n][r] + bb;
                    const float g = 0.5f * u * (1.f + erff(u * 0.70710678118654752f));
                    *(unsigned short*)(smem + i * 768 + ((c * 2) ^ ((i & 7) << 4))) = f2bf(g);
                }
            }
        }
    }
    __syncthreads();
    // GEMM2 (384 -> 192) + residual: wave -> rows [32mh,+32) x cols [(w>>1)*48, +48)
    {
        const int cbase = (wave >> 1) * 48;
        f32x4 acc[2][3] = {};
        #pragma unroll
        for (int ks = 0; ks < 12; ++ks) {
            bf16x8 af[2];
            const int kbyte = ks * 64 + lhi * 16;
            #pragma unroll
            for (int m = 0; m < 2; ++m) {
                const int row = (mh * 2 + m) * 16 + llo;
                af[m] = *(const bf16x8*)(smem + row * 768 + (kbyte ^ ((row & 7) << 4)));
            }
            #pragma unroll
            for (int n = 0; n < 3; ++n) {
                const int col = cbase + n * 16 + llo;
                const bf16x8 bfr = *(const bf16x8*)(w2T + col * 384 + ks * 32 + lhi * 8);
                #pragma unroll
                for (int m = 0; m < 2; ++m) acc[m][n] = mfma16(af[m], bfr, acc[m][n]);
            }
        }
        #pragma unroll
        for (int n = 0; n < 3; ++n) {
            const int c = cbase + n * 16 + llo;
            const float bb = b2[c];
            #pragma unroll
            for (int m = 0; m < 2; ++m) {
                #pragma unroll
                for (int r = 0; r < 4; ++r) {
                    const int i = (mh * 2 + m) * 16 + lhi * 4 + r;
                    float* p = io + (t0 + i) * CC + c;
                    *p = *p + acc[m][n][r] + bb;
                }
            }
        }
    }
}

extern "C" void kernel_launch(void* const* d_in, const int* in_sizes, int n_in,
                              void* d_out, int out_size, void* d_ws, size_t ws_size,
                              hipStream_t stream)
{
    const float* x      = (const float*)d_in[0];
    const float* n1g    = (const float*)d_in[1];
    const float* n1b    = (const float*)d_in[2];
    const float* qkv_w  = (const float*)d_in[3];
    const float* qkv_b  = (const float*)d_in[4];
    const float* proj_w = (const float*)d_in[5];
    const float* proj_b = (const float*)d_in[6];
    const float* relTab = (const float*)d_in[7];
    const float* n2g    = (const float*)d_in[8];
    const float* n2b    = (const float*)d_in[9];
    const float* w1     = (const float*)d_in[10];
    const float* b1     = (const float*)d_in[11];
    const float* w2     = (const float*)d_in[12];
    const float* b2     = (const float*)d_in[13];
    float* out = (float*)d_out;

    char* ws = (char*)d_ws;
    unsigned short* qkvT  = (unsigned short*)(ws);            // [576][192] bf16
    unsigned short* projT = (unsigned short*)(ws + 221184);   // [192][192] bf16
    unsigned short* w1T   = (unsigned short*)(ws + 294912);   // [384][192] bf16
    unsigned short* w2T   = (unsigned short*)(ws + 442368);   // [192][384] bf16
    float*          biasT = (float*)(ws + 589824);            // [6][64][64] f32

    k_prep<<<1248, 256, 0, stream>>>(qkv_w, proj_w, w1, w2, relTab, qkvT, projT, w1T, w2T, biasT);
    k_attn<<<2048, 384, 0, stream>>>(x, n1g, n1b, qkvT, qkv_b, projT, proj_b, biasT, out);
    k_mlp<<<2048, 512, 0, stream>>>(n2g, n2b, w1T, b1, w2T, b2, out);
}

// Round 8
// 403.323 us; speedup vs baseline: 1.1952x; 1.1952x over previous
//
#include <hip/hip_runtime.h>
#include <hip/hip_bf16.h>

#define CC 192

typedef __attribute__((ext_vector_type(8))) short bf16x8;
typedef __attribute__((ext_vector_type(4))) float f32x4;

__device__ __forceinline__ unsigned short f2bf(float f) {
    unsigned int u = __float_as_uint(f);
    u = (u + 0x7fffu + ((u >> 16) & 1u)) >> 16;
    return (unsigned short)u;
}

__device__ __forceinline__ f32x4 mfma16(bf16x8 a, bf16x8 b, f32x4 c) {
    return __builtin_amdgcn_mfma_f32_16x16x32_bf16(a, b, c, 0, 0, 0);
}

// Merged prep: 4 weight transposes (f32 [K][N] -> bf16 [N][K]) + bias expand.
__global__ void k_prep(const float* __restrict__ qkv_w, const float* __restrict__ proj_w,
                       const float* __restrict__ w1, const float* __restrict__ w2,
                       const float* __restrict__ relTab,
                       unsigned short* __restrict__ qkvT, unsigned short* __restrict__ projT,
                       unsigned short* __restrict__ w1T, unsigned short* __restrict__ w2T,
                       float* __restrict__ biasT) {
    int idx = blockIdx.x * blockDim.x + threadIdx.x;
    if (idx < 110592) { int n = idx / 192, k = idx % 192; qkvT[idx] = f2bf(qkv_w[k * 576 + n]); return; }
    idx -= 110592;
    if (idx < 36864)  { int n = idx / 192, k = idx % 192; projT[idx] = f2bf(proj_w[k * 192 + n]); return; }
    idx -= 36864;
    if (idx < 73728)  { int n = idx / 192, k = idx % 192; w1T[idx] = f2bf(w1[k * 384 + n]); return; }
    idx -= 73728;
    if (idx < 73728)  { int n = idx / 384, k = idx % 384; w2T[idx] = f2bf(w2[k * 192 + n]); return; }
    idx -= 73728;
    if (idx < 24576) {
        int h = idx >> 12, i = (idx >> 6) & 63, j = idx & 63;
        int yi = i >> 3, xi = i & 7, yj = j >> 3, xj = j & 7;
        int rel = (yi - yj + 7) * 15 + (xi - xj + 7);
        biasT[idx] = relTab[rel * 6 + h];
    }
}

// One window per block (2048 blocks), 12 waves (2 waves per head in attention).
// LDS = TWO 24 KiB regions (49.6 KB total -> 2 blocks/CU, proven R5):
//   R1 [24576 B]: A (swz [64][192] bf16) -> VT (swz [6][32][64], 4096 B/head) -> AO (swz [64][192])
//   R2 [24576 B]: Q (swz [6][64][32]) -> K (same layout) -> P-half (swz [6][64][32])
// vs R5: attention phase register-slimmed (P-half0 written to LDS inside softmax loop,
// only half1 kept packed; no-max softmax; SCALE folded into Q) to fit the 85-VGPR cap
// without spilling.
__global__ __launch_bounds__(768, 6) void k_attn(
    const float* __restrict__ x,
    const float* __restrict__ n1g, const float* __restrict__ n1b,
    const unsigned short* __restrict__ qkvT, const float* __restrict__ qkv_b,
    const unsigned short* __restrict__ projT, const float* __restrict__ proj_b,
    const float* __restrict__ biasTab,
    float* __restrict__ out)
{
    __shared__ __align__(16) char smem[49152];
    __shared__ int sOpos[64];
    char* const R1 = smem;
    char* const R2 = smem + 24576;

    const int tid = threadIdx.x;
    const int wid = blockIdx.x;
    const int b = wid >> 6;
    const int win = wid & 63;
    const int wh = win >> 3, ww = win & 7;
    const int lane = tid & 63;
    const int wave = tid >> 6;
    const int lhi = lane >> 4, llo = lane & 15;

    // ---------- Phase 1: LN1 + shifted window gather (512 threads, 8/token) ----------
    if (tid < 512) {
        const int tok = tid >> 3;
        const int ch0 = (tid & 7) * 24;
        const int yi = tok >> 3, xi = tok & 7;
        const int oy = (wh * 8 + yi + 4) & 63;
        const int ox = (ww * 8 + xi + 4) & 63;
        const int base = ((b * 64 + oy) * 64 + ox) * CC;
        if ((tid & 7) == 0) sOpos[tok] = base;
        float v[24];
        float s = 0.f, ss = 0.f;
        #pragma unroll
        for (int i = 0; i < 6; ++i) {
            const float4 f = *(const float4*)(x + base + ch0 + i * 4);
            v[i*4+0]=f.x; v[i*4+1]=f.y; v[i*4+2]=f.z; v[i*4+3]=f.w;
            s  += f.x + f.y + f.z + f.w;
            ss += f.x*f.x + f.y*f.y + f.z*f.z + f.w*f.w;
        }
        s  += __shfl_xor(s, 1);  s  += __shfl_xor(s, 2);  s  += __shfl_xor(s, 4);
        ss += __shfl_xor(ss, 1); ss += __shfl_xor(ss, 2); ss += __shfl_xor(ss, 4);
        const float mean = s * (1.f / 192.f);
        const float rstd = rsqrtf(ss * (1.f / 192.f) - mean * mean + 1e-5f);
        char* aBase = R1 + tok * 384;
        const int sw = (tok & 7) << 4;
        #pragma unroll
        for (int i = 0; i < 12; ++i) {
            const int c = ch0 + i * 2;
            const float a0 = (v[i*2+0] - mean) * rstd * n1g[c]   + n1b[c];
            const float a1 = (v[i*2+1] - mean) * rstd * n1g[c+1] + n1b[c+1];
            *(unsigned int*)(aBase + ((c * 2) ^ sw)) =
                (unsigned int)f2bf(a0) | ((unsigned int)f2bf(a1) << 16);
        }
    }
    __syncthreads();   // bar1: A ready

    // ---------- Phase 2: QKV GEMM, wave w -> cols [48w, 48w+48) ----------
    const int cbase = wave * 48;
    const int which = wave >> 2;          // 0:Q 1:K 2:V (48-col blocks don't straddle)
    {
        f32x4 acc[4][3] = {};
        #pragma unroll
        for (int ks = 0; ks < 6; ++ks) {
            bf16x8 af[4];
            const int kbyte = ks * 64 + lhi * 16;
            #pragma unroll
            for (int m = 0; m < 4; ++m) {
                const int row = m * 16 + llo;
                af[m] = *(const bf16x8*)(R1 + row * 384 + (kbyte ^ ((row & 7) << 4)));
            }
            #pragma unroll
            for (int n = 0; n < 3; ++n) {
                const int col = cbase + n * 16 + llo;
                const bf16x8 bfr = *(const bf16x8*)(qkvT + col * 192 + ks * 32 + lhi * 8);
                #pragma unroll
                for (int m = 0; m < 4; ++m) acc[m][n] = mfma16(af[m], bfr, acc[m][n]);
            }
        }
        // ---- epilogue-a: waves 0-3 scatter Q (xSCALE +bias) -> R2 (R2 fresh) ----
        if (which == 0) {
            #pragma unroll
            for (int n = 0; n < 3; ++n) {
                const int c0 = cbase + n * 16;
                const int h = c0 >> 5;
                const int d = (c0 & 31) + llo;
                const float bia = qkv_b[c0 + llo];
                #pragma unroll
                for (int m = 0; m < 4; ++m) {
                    #pragma unroll
                    for (int r = 0; r < 4; ++r) {
                        const int row = m * 16 + lhi * 4 + r;
                        *(unsigned short*)(R2 + h * 4096 + row * 64 + ((2 * d) ^ ((row & 3) << 4)))
                            = f2bf((acc[m][n][r] + bia) * 0.17677669529663687f);
                    }
                }
            }
        }
        __syncthreads();   // bar2: Q visible; A consumed by all waves

        // all waves load their Q fragments
        const int h = wave >> 1;
        const int mh = wave & 1;
        bf16x8 qf[2];
        #pragma unroll
        for (int m = 0; m < 2; ++m) {
            const int t = (mh * 2 + m) * 16 + llo;
            qf[m] = *(const bf16x8*)(R2 + h * 4096 + t * 64 + ((lhi * 16) ^ ((t & 3) << 4)));
        }
        // waves 8-11 scatter VT -> R1 (A dead)
        if (which == 2) {
            #pragma unroll
            for (int n = 0; n < 3; ++n) {
                const int c0 = cbase + n * 16;
                const int rem = c0 - 384;
                const int hh = rem >> 5;
                const int d = (rem & 31) + llo;
                const float bia = qkv_b[c0 + llo];
                #pragma unroll
                for (int m = 0; m < 4; ++m) {
                    #pragma unroll
                    for (int r = 0; r < 4; ++r) {
                        const int row = m * 16 + lhi * 4 + r;
                        *(unsigned short*)(R1 + hh * 4096 + d * 128 + ((2 * row) ^ ((d & 7) << 4)))
                            = f2bf(acc[m][n][r] + bia);
                    }
                }
            }
        }
        __syncthreads();   // bar3: qf loaded everywhere -> R2 free; VT visible

        // waves 4-7 scatter K -> R2
        if (which == 1) {
            #pragma unroll
            for (int n = 0; n < 3; ++n) {
                const int c0 = cbase + n * 16;
                const int rem = c0 - 192;
                const int hh = rem >> 5;
                const int d = (rem & 31) + llo;
                const float bia = qkv_b[c0 + llo];
                #pragma unroll
                for (int m = 0; m < 4; ++m) {
                    #pragma unroll
                    for (int r = 0; r < 4; ++r) {
                        const int row = m * 16 + lhi * 4 + r;
                        *(unsigned short*)(R2 + hh * 4096 + row * 64 + ((2 * d) ^ ((row & 3) << 4)))
                            = f2bf(acc[m][n][r] + bia);
                    }
                }
            }
        }
        __syncthreads();   // bar4: K visible

        // ---------- Phase 3: attention (head = wave>>1, row-half = wave&1) ----------
        bf16x8 kf[4];
        #pragma unroll
        for (int n = 0; n < 4; ++n) {
            const int t = n * 16 + llo;
            kf[n] = *(const bf16x8*)(R2 + h * 4096 + t * 64 + ((lhi * 16) ^ ((t & 3) << 4)));
        }
        __syncthreads();   // bar5: kf loaded everywhere -> R2 free for P

        f32x4 sacc[2][4] = {};
        #pragma unroll
        for (int m = 0; m < 2; ++m)
            #pragma unroll
            for (int n = 0; n < 4; ++n)
                sacc[m][n] = mfma16(qf[m], kf[n], sacc[m][n]);

        const bool eH = (wh == 7), eW = (ww == 7);
        int idj[4];
        #pragma unroll
        for (int n = 0; n < 4; ++n) {
            const int j = n * 16 + llo;
            idj[n] = (eH ? ((j >> 3) >= 4 ? 2 : 1) : 0) * 3 + (eW ? ((j & 7) >= 4 ? 2 : 1) : 0);
        }
        const float* bT = biasTab + h * 4096;
        // no-max softmax (scores O(1), f32-exp exact); P-half0 -> LDS inline, half1 packed.
        unsigned pbp[2][4];
        float rinv[2][4];
        #pragma unroll
        for (int m = 0; m < 2; ++m) {
            #pragma unroll
            for (int r = 0; r < 4; ++r) {
                const int i = (mh * 2 + m) * 16 + lhi * 4 + r;
                const int idi = (eH ? ((i >> 3) >= 4 ? 2 : 1) : 0) * 3 +
                                (eW ? ((i & 7) >= 4 ? 2 : 1) : 0);
                float sum = 0.f;
                unsigned short pb[4];
                #pragma unroll
                for (int n = 0; n < 4; ++n) {
                    const int j = n * 16 + llo;
                    float e = __expf(sacc[m][n][r] + bT[i * 64 + j]);
                    if (idi != idj[n]) e = 0.f;
                    sum += e;
                    pb[n] = f2bf(e);
                }
                sum += __shfl_xor(sum, 1);
                sum += __shfl_xor(sum, 2);
                sum += __shfl_xor(sum, 4);
                sum += __shfl_xor(sum, 8);
                rinv[m][r] = 1.f / sum;
                char* base = R2 + h * 4096 + i * 64;
                const int sw = (i & 3) << 4;
                *(unsigned short*)(base + ((2 * llo) ^ sw)) = pb[0];
                *(unsigned short*)(base + ((2 * (16 + llo)) ^ sw)) = pb[1];
                pbp[m][r] = (unsigned)pb[2] | ((unsigned)pb[3] << 16);
            }
        }

        // PV half0: P[:,0:32] x V[0:32,:]  (wave-private LDS, no barrier)
        f32x4 pacc[2][2] = {};
        {
            bf16x8 pf[2];
            #pragma unroll
            for (int m = 0; m < 2; ++m) {
                const int t = (mh * 2 + m) * 16 + llo;
                pf[m] = *(const bf16x8*)(R2 + h * 4096 + t * 64 + ((lhi * 16) ^ ((t & 3) << 4)));
            }
            #pragma unroll
            for (int n = 0; n < 2; ++n) {
                const int d = n * 16 + llo;
                const bf16x8 vf = *(const bf16x8*)(R1 + h * 4096 + d * 128 + ((lhi * 16) ^ ((d & 7) << 4)));
                #pragma unroll
                for (int m = 0; m < 2; ++m) pacc[m][n] = mfma16(pf[m], vf, pacc[m][n]);
            }
        }
        // write P-half1 (overwrite own rows), then PV half1
        #pragma unroll
        for (int m = 0; m < 2; ++m) {
            #pragma unroll
            for (int r = 0; r < 4; ++r) {
                const int i = (mh * 2 + m) * 16 + lhi * 4 + r;
                char* base = R2 + h * 4096 + i * 64;
                const int sw = (i & 3) << 4;
                const unsigned u = pbp[m][r];
                *(unsigned short*)(base + ((2 * llo) ^ sw)) = (unsigned short)u;
                *(unsigned short*)(base + ((2 * (16 + llo)) ^ sw)) = (unsigned short)(u >> 16);
            }
        }
        {
            bf16x8 pf[2];
            #pragma unroll
            for (int m = 0; m < 2; ++m) {
                const int t = (mh * 2 + m) * 16 + llo;
                pf[m] = *(const bf16x8*)(R2 + h * 4096 + t * 64 + ((lhi * 16) ^ ((t & 3) << 4)));
            }
            #pragma unroll
            for (int n = 0; n < 2; ++n) {
                const int d = n * 16 + llo;
                const bf16x8 vf = *(const bf16x8*)(R1 + h * 4096 + d * 128 + ((64 + lhi * 16) ^ ((d & 7) << 4)));
                #pragma unroll
                for (int m = 0; m < 2; ++m) pacc[m][n] = mfma16(pf[m], vf, pacc[m][n]);
            }
        }
        __syncthreads();   // bar6: PV done everywhere -> R1 (VT) free, R2 (P) free

        // AO -> R1 (swz [64][192])
        #pragma unroll
        for (int m = 0; m < 2; ++m) {
            #pragma unroll
            for (int n = 0; n < 2; ++n) {
                const int c = h * 32 + n * 16 + llo;
                #pragma unroll
                for (int r = 0; r < 4; ++r) {
                    const int i = (mh * 2 + m) * 16 + lhi * 4 + r;
                    *(unsigned short*)(R1 + i * 384 + ((c * 2) ^ ((i & 7) << 4)))
                        = f2bf(pacc[m][n][r] * rinv[m][r]);
                }
            }
        }
    }
    __syncthreads();   // bar7: AO ready

    // ---------- Phase 4: proj GEMM + residual, wave w -> cols [16w, 16w+16) ----------
    {
        const int pcbase = wave * 16;
        f32x4 acc[4] = {};
        #pragma unroll
        for (int ks = 0; ks < 6; ++ks) {
            bf16x8 af[4];
            const int kbyte = ks * 64 + lhi * 16;
            #pragma unroll
            for (int m = 0; m < 4; ++m) {
                const int row = m * 16 + llo;
                af[m] = *(const bf16x8*)(R1 + row * 384 + (kbyte ^ ((row & 7) << 4)));
            }
            const int col = pcbase + llo;
            const bf16x8 bfr = *(const bf16x8*)(projT + col * 192 + ks * 32 + lhi * 8);
            #pragma unroll
            for (int m = 0; m < 4; ++m) acc[m] = mfma16(af[m], bfr, acc[m]);
        }
        const int c = pcbase + llo;
        const float pb = proj_b[c];
        #pragma unroll
        for (int m = 0; m < 4; ++m) {
            #pragma unroll
            for (int r = 0; r < 4; ++r) {
                const int i = m * 16 + lhi * 4 + r;
                const int base = sOpos[i];
                out[base + c] = x[base + c] + acc[m][r] + pb;
            }
        }
    }
}

// 64 tokens per block, 8 waves (2 waves per row-half group). In-place on io.
// LDS: one 48 KiB region: A (swz [64][192], first 24 KiB) -> G (swz [64][384], all 48 KiB).
__global__ __launch_bounds__(512, 4) void k_mlp(
    const float* __restrict__ n2g, const float* __restrict__ n2b,
    const unsigned short* __restrict__ w1T, const float* __restrict__ b1,
    const unsigned short* __restrict__ w2T, const float* __restrict__ b2,
    float* __restrict__ io)
{
    __shared__ __align__(16) char smem[49152];
    const int tid = threadIdx.x;
    const int lane = tid & 63, wave = tid >> 6;
    const int lhi = lane >> 4, llo = lane & 15;
    const int mh = wave & 1;
    const long t0 = (long)blockIdx.x * 64;

    {
        const int tok = tid >> 3;
        const int ch0 = (tid & 7) * 24;
        const float* hp = io + (t0 + tok) * CC;
        float v[24]; float s = 0.f, ss = 0.f;
        #pragma unroll
        for (int i = 0; i < 6; ++i) {
            const float4 f = *(const float4*)(hp + ch0 + i * 4);
            v[i*4]=f.x; v[i*4+1]=f.y; v[i*4+2]=f.z; v[i*4+3]=f.w;
            s += f.x + f.y + f.z + f.w;
            ss += f.x*f.x + f.y*f.y + f.z*f.z + f.w*f.w;
        }
        s  += __shfl_xor(s, 1);  s  += __shfl_xor(s, 2);  s  += __shfl_xor(s, 4);
        ss += __shfl_xor(ss, 1); ss += __shfl_xor(ss, 2); ss += __shfl_xor(ss, 4);
        const float mean = s * (1.f / 192.f);
        const float rstd = rsqrtf(ss * (1.f / 192.f) - mean * mean + 1e-5f);
        char* aBase = smem + tok * 384;
        const int sw = (tok & 7) << 4;
        #pragma unroll
        for (int i = 0; i < 12; ++i) {
            const int c = ch0 + i * 2;
            const float a0 = (v[i*2]   - mean) * rstd * n2g[c]   + n2b[c];
            const float a1 = (v[i*2+1] - mean) * rstd * n2g[c+1] + n2b[c+1];
            *(unsigned int*)(aBase + ((c * 2) ^ sw)) =
                (unsigned int)f2bf(a0) | ((unsigned int)f2bf(a1) << 16);
        }
    }
    __syncthreads();
    // GEMM1 (192 -> 384) + exact GELU: wave -> rows [32mh,32mh+32) x cols [(w>>1)*96, +96)
    {
        const int cbase = (wave >> 1) * 96;
        f32x4 acc[2][6] = {};
        #pragma unroll
        for (int ks = 0; ks < 6; ++ks) {
            bf16x8 af[2];
            const int kbyte = ks * 64 + lhi * 16;
            #pragma unroll
            for (int m = 0; m < 2; ++m) {
                const int row = (mh * 2 + m) * 16 + llo;
                af[m] = *(const bf16x8*)(smem + row * 384 + (kbyte ^ ((row & 7) << 4)));
            }
            #pragma unroll
            for (int n = 0; n < 6; ++n) {
                const int col = cbase + n * 16 + llo;
                const bf16x8 bfr = *(const bf16x8*)(w1T + col * 192 + ks * 32 + lhi * 8);
                #pragma unroll
                for (int m = 0; m < 2; ++m) acc[m][n] = mfma16(af[m], bfr, acc[m][n]);
            }
        }
        __syncthreads();   // A consumed; region free for G
        #pragma unroll
        for (int n = 0; n < 6; ++n) {
            const int c = cbase + n * 16 + llo;
            const float bb = b1[c];
            #pragma unroll
            for (int m = 0; m < 2; ++m) {
                #pragma unroll
                for (int r = 0; r < 4; ++r) {
                    const int i = (mh * 2 + m) * 16 + lhi * 4 + r;
                    const float u = acc[m][n][r] + bb;
                    const float g = 0.5f * u * (1.f + erff(u * 0.70710678118654752f));
                    *(unsigned short*)(smem + i * 768 + ((c * 2) ^ ((i & 7) << 4))) = f2bf(g);
                }
            }
        }
    }
    __syncthreads();
    // GEMM2 (384 -> 192) + residual: wave -> rows [32mh,+32) x cols [(w>>1)*48, +48)
    {
        const int cbase = (wave >> 1) * 48;
        f32x4 acc[2][3] = {};
        #pragma unroll
        for (int ks = 0; ks < 12; ++ks) {
            bf16x8 af[2];
            const int kbyte = ks * 64 + lhi * 16;
            #pragma unroll
            for (int m = 0; m < 2; ++m) {
                const int row = (mh * 2 + m) * 16 + llo;
                af[m] = *(const bf16x8*)(smem + row * 768 + (kbyte ^ ((row & 7) << 4)));
            }
            #pragma unroll
            for (int n = 0; n < 3; ++n) {
                const int col = cbase + n * 16 + llo;
                const bf16x8 bfr = *(const bf16x8*)(w2T + col * 384 + ks * 32 + lhi * 8);
                #pragma unroll
                for (int m = 0; m < 2; ++m) acc[m][n] = mfma16(af[m], bfr, acc[m][n]);
            }
        }
        #pragma unroll
        for (int n = 0; n < 3; ++n) {
            const int c = cbase + n * 16 + llo;
            const float bb = b2[c];
            #pragma unroll
            for (int m = 0; m < 2; ++m) {
                #pragma unroll
                for (int r = 0; r < 4; ++r) {
                    const int i = (mh * 2 + m) * 16 + lhi * 4 + r;
                    float* p = io + (t0 + i) * CC + c;
                    *p = *p + acc[m][n][r] + bb;
                }
            }
        }
    }
}

extern "C" void kernel_launch(void* const* d_in, const int* in_sizes, int n_in,
                              void* d_out, int out_size, void* d_ws, size_t ws_size,
                              hipStream_t stream)
{
    const float* x      = (const float*)d_in[0];
    const float* n1g    = (const float*)d_in[1];
    const float* n1b    = (const float*)d_in[2];
    const float* qkv_w  = (const float*)d_in[3];
    const float* qkv_b  = (const float*)d_in[4];
    const float* proj_w = (const float*)d_in[5];
    const float* proj_b = (const float*)d_in[6];
    const float* relTab = (const float*)d_in[7];
    const float* n2g    = (const float*)d_in[8];
    const float* n2b    = (const float*)d_in[9];
    const float* w1     = (const float*)d_in[10];
    const float* b1     = (const float*)d_in[11];
    const float* w2     = (const float*)d_in[12];
    const float* b2     = (const float*)d_in[13];
    float* out = (float*)d_out;

    char* ws = (char*)d_ws;
    unsigned short* qkvT  = (unsigned short*)(ws);            // [576][192] bf16
    unsigned short* projT = (unsigned short*)(ws + 221184);   // [192][192] bf16
    unsigned short* w1T   = (unsigned short*)(ws + 294912);   // [384][192] bf16
    unsigned short* w2T   = (unsigned short*)(ws + 442368);   // [192][384] bf16
    float*          biasT = (float*)(ws + 589824);            // [6][64][64] f32

    k_prep<<<1248, 256, 0, stream>>>(qkv_w, proj_w, w1, w2, relTab, qkvT, projT, w1T, w2T, biasT);
    k_attn<<<2048, 768, 0, stream>>>(x, n1g, n1b, qkvT, qkv_b, projT, proj_b, biasT, out);
    k_mlp<<<2048, 512, 0, stream>>>(n2g, n2b, w1T, b1, w2T, b2, out);
}

// Round 9
// 296.996 us; speedup vs baseline: 1.6231x; 1.3580x over previous
//
#include <hip/hip_runtime.h>
#include <hip/hip_bf16.h>

#define CC 192

typedef __attribute__((ext_vector_type(8))) short bf16x8;
typedef __attribute__((ext_vector_type(4))) float f32x4;

__device__ __forceinline__ unsigned short f2bf(float f) {
    unsigned int u = __float_as_uint(f);
    u = (u + 0x7fffu + ((u >> 16) & 1u)) >> 16;
    return (unsigned short)u;
}

__device__ __forceinline__ f32x4 mfma16(bf16x8 a, bf16x8 b, f32x4 c) {
    return __builtin_amdgcn_mfma_f32_16x16x32_bf16(a, b, c, 0, 0, 0);
}

// Merged prep: 4 weight transposes (f32 [K][N] -> bf16 [N][K]) + bias expand.
__global__ void k_prep(const float* __restrict__ qkv_w, const float* __restrict__ proj_w,
                       const float* __restrict__ w1, const float* __restrict__ w2,
                       const float* __restrict__ relTab,
                       unsigned short* __restrict__ qkvT, unsigned short* __restrict__ projT,
                       unsigned short* __restrict__ w1T, unsigned short* __restrict__ w2T,
                       float* __restrict__ biasT) {
    int idx = blockIdx.x * blockDim.x + threadIdx.x;
    if (idx < 110592) { int n = idx / 192, k = idx % 192; qkvT[idx] = f2bf(qkv_w[k * 576 + n]); return; }
    idx -= 110592;
    if (idx < 36864)  { int n = idx / 192, k = idx % 192; projT[idx] = f2bf(proj_w[k * 192 + n]); return; }
    idx -= 36864;
    if (idx < 73728)  { int n = idx / 192, k = idx % 192; w1T[idx] = f2bf(w1[k * 384 + n]); return; }
    idx -= 73728;
    if (idx < 73728)  { int n = idx / 384, k = idx % 384; w2T[idx] = f2bf(w2[k * 192 + n]); return; }
    idx -= 73728;
    if (idx < 24576) {
        int h = idx >> 12, i = (idx >> 6) & 63, j = idx & 63;
        int yi = i >> 3, xi = i & 7, yj = j >> 3, xj = j & 7;
        int rel = (yi - yj + 7) * 15 + (xi - xj + 7);
        biasT[idx] = relTab[rel * 6 + h];
    }
}

// FUSED Swin block: one window per block (2048 blocks), 12 waves (768 threads).
// Attention part = R4's proven structure (201 us); MLP appended in-block, reusing LDS.
// LDS regions by phase lifetime:
//   rA [24 KB]: A (swz [64][192]) -> VT (swz [6][32][64]) -> AO (swz [64][192]) -> A2 (LN2 out)
//   rQ [24 KB]: Q (swz [6][64][32]) -> P (swz [6][64][64], 8 KB/head, spans rQ+rK) -> G[0:24K]
//   rK [24 KB]: K (swz [6][64][32]) -> P cont. -> G[24K:48K]
__global__ __launch_bounds__(768, 3) void k_fused(
    const float* __restrict__ x,
    const float* __restrict__ n1g, const float* __restrict__ n1b,
    const unsigned short* __restrict__ qkvT, const float* __restrict__ qkv_b,
    const unsigned short* __restrict__ projT, const float* __restrict__ proj_b,
    const float* __restrict__ biasTab,
    const float* __restrict__ n2g, const float* __restrict__ n2b,
    const unsigned short* __restrict__ w1T, const float* __restrict__ b1,
    const unsigned short* __restrict__ w2T, const float* __restrict__ b2,
    float* __restrict__ out)
{
    __shared__ __align__(16) char smem[73728];
    __shared__ int sOpos[64];
    char* const rA = smem;
    char* const rQ = smem + 24576;
    char* const rK = smem + 49152;
    char* const rG = smem + 24576;   // G = rQ+rK (48 KB), alive only in MLP phases

    const int tid = threadIdx.x;
    const int wid = blockIdx.x;
    const int b = wid >> 6;
    const int win = wid & 63;
    const int wh = win >> 3, ww = win & 7;
    const int lane = tid & 63;
    const int wave = tid >> 6;
    const int lhi = lane >> 4, llo = lane & 15;

    // ---------- Phase 1: LN1 + shifted window gather (512 threads, 8/token) ----------
    if (tid < 512) {
        const int tok = tid >> 3;
        const int ch0 = (tid & 7) * 24;
        const int yi = tok >> 3, xi = tok & 7;
        const int oy = (wh * 8 + yi + 4) & 63;
        const int ox = (ww * 8 + xi + 4) & 63;
        const int base = ((b * 64 + oy) * 64 + ox) * CC;
        if ((tid & 7) == 0) sOpos[tok] = base;
        float v[24];
        float s = 0.f, ss = 0.f;
        #pragma unroll
        for (int i = 0; i < 6; ++i) {
            const float4 f = *(const float4*)(x + base + ch0 + i * 4);
            v[i*4+0]=f.x; v[i*4+1]=f.y; v[i*4+2]=f.z; v[i*4+3]=f.w;
            s  += f.x + f.y + f.z + f.w;
            ss += f.x*f.x + f.y*f.y + f.z*f.z + f.w*f.w;
        }
        s  += __shfl_xor(s, 1);  s  += __shfl_xor(s, 2);  s  += __shfl_xor(s, 4);
        ss += __shfl_xor(ss, 1); ss += __shfl_xor(ss, 2); ss += __shfl_xor(ss, 4);
        const float mean = s * (1.f / 192.f);
        const float rstd = rsqrtf(ss * (1.f / 192.f) - mean * mean + 1e-5f);
        char* aBase = rA + tok * 384;
        const int sw = (tok & 7) << 4;
        #pragma unroll
        for (int i = 0; i < 12; ++i) {
            const int c = ch0 + i * 2;
            const float a0 = (v[i*2+0] - mean) * rstd * n1g[c]   + n1b[c];
            const float a1 = (v[i*2+1] - mean) * rstd * n1g[c+1] + n1b[c+1];
            *(unsigned int*)(aBase + ((c * 2) ^ sw)) =
                (unsigned int)f2bf(a0) | ((unsigned int)f2bf(a1) << 16);
        }
    }
    __syncthreads();   // bar1: A ready

    // ---------- Phase 2: QKV GEMM, wave w -> cols [48w, 48w+48) ----------
    {
        const int cbase = wave * 48;
        f32x4 acc[4][3] = {};
        #pragma unroll
        for (int ks = 0; ks < 6; ++ks) {
            bf16x8 af[4];
            const int kbyte = ks * 64 + lhi * 16;
            #pragma unroll
            for (int m = 0; m < 4; ++m) {
                const int row = m * 16 + llo;
                af[m] = *(const bf16x8*)(rA + row * 384 + (kbyte ^ ((row & 7) << 4)));
            }
            #pragma unroll
            for (int n = 0; n < 3; ++n) {
                const int col = cbase + n * 16 + llo;
                const bf16x8 bfr = *(const bf16x8*)(qkvT + col * 192 + ks * 32 + lhi * 8);
                #pragma unroll
                for (int m = 0; m < 4; ++m) acc[m][n] = mfma16(af[m], bfr, acc[m][n]);
            }
        }
        __syncthreads();   // bar2: A fully consumed; rA region free for VT
        // epilogue: +bias, scatter to Q/K/VT LDS (SCALE folded into Q)
        #pragma unroll
        for (int n = 0; n < 3; ++n) {
            const int c0 = cbase + n * 16;
            const int which = c0 / 192;
            const int rem = c0 - which * 192;
            const int h = rem >> 5;
            const int d = (rem & 31) + llo;
            const float bia = qkv_b[c0 + llo];
            #pragma unroll
            for (int m = 0; m < 4; ++m) {
                #pragma unroll
                for (int r = 0; r < 4; ++r) {
                    const int row = m * 16 + lhi * 4 + r;
                    if (which == 0)
                        *(unsigned short*)(rQ + h * 4096 + row * 64 + ((2 * d) ^ ((row & 3) << 4)))
                            = f2bf((acc[m][n][r] + bia) * 0.17677669529663687f);
                    else if (which == 1)
                        *(unsigned short*)(rK + h * 4096 + row * 64 + ((2 * d) ^ ((row & 3) << 4)))
                            = f2bf(acc[m][n][r] + bia);
                    else
                        *(unsigned short*)(rA + h * 4096 + d * 128 + ((2 * row) ^ ((d & 7) << 4)))
                            = f2bf(acc[m][n][r] + bia);
                }
            }
        }
    }
    __syncthreads();   // bar3: Q/K/VT visible

    // ---------- Phase 3: attention (head = wave>>1, row-half = wave&1) ----------
    const int h = wave >> 1;
    const int mh = wave & 1;
    f32x4 pacc[2][2] = {};
    float rinv[2][4];
    {
        bf16x8 qf[2], kf[4];
        #pragma unroll
        for (int m = 0; m < 2; ++m) {
            const int t = (mh * 2 + m) * 16 + llo;
            qf[m] = *(const bf16x8*)(rQ + h * 4096 + t * 64 + ((lhi * 16) ^ ((t & 3) << 4)));
        }
        #pragma unroll
        for (int n = 0; n < 4; ++n) {
            const int t = n * 16 + llo;
            kf[n] = *(const bf16x8*)(rK + h * 4096 + t * 64 + ((lhi * 16) ^ ((t & 3) << 4)));
        }
        __syncthreads();   // bar4: Q/K in registers everywhere; rQ+rK free for P

        f32x4 sacc[2][4] = {};
        #pragma unroll
        for (int m = 0; m < 2; ++m)
            #pragma unroll
            for (int n = 0; n < 4; ++n)
                sacc[m][n] = mfma16(qf[m], kf[n], sacc[m][n]);

        const bool eH = (wh == 7), eW = (ww == 7);
        int idj[4];
        #pragma unroll
        for (int n = 0; n < 4; ++n) {
            const int j = n * 16 + llo;
            idj[n] = (eH ? ((j >> 3) >= 4 ? 2 : 1) : 0) * 3 + (eW ? ((j & 7) >= 4 ? 2 : 1) : 0);
        }
        const float* bT = biasTab + h * 4096;
        // no-max softmax (scores O(1), f32-exp exact)
        #pragma unroll
        for (int m = 0; m < 2; ++m) {
            #pragma unroll
            for (int r = 0; r < 4; ++r) {
                const int i = (mh * 2 + m) * 16 + lhi * 4 + r;
                const int idi = (eH ? ((i >> 3) >= 4 ? 2 : 1) : 0) * 3 +
                                (eW ? ((i & 7) >= 4 ? 2 : 1) : 0);
                float sum = 0.f;
                unsigned short pb[4];
                #pragma unroll
                for (int n = 0; n < 4; ++n) {
                    const int j = n * 16 + llo;
                    float e = __expf(sacc[m][n][r] + bT[i * 64 + j]);
                    if (idi != idj[n]) e = 0.f;
                    sum += e;
                    pb[n] = f2bf(e);
                }
                sum += __shfl_xor(sum, 1);
                sum += __shfl_xor(sum, 2);
                sum += __shfl_xor(sum, 4);
                sum += __shfl_xor(sum, 8);
                rinv[m][r] = 1.f / sum;
                #pragma unroll
                for (int n = 0; n < 4; ++n) {
                    const int j = n * 16 + llo;
                    *(unsigned short*)(rQ + h * 8192 + i * 128 + ((2 * j) ^ ((i & 7) << 4))) = pb[n];
                }
            }
        }
        // P is wave-private (own 32 rows) -> no barrier before PV.
        #pragma unroll
        for (int ks = 0; ks < 2; ++ks) {
            bf16x8 pf[2];
            #pragma unroll
            for (int m = 0; m < 2; ++m) {
                const int t = (mh * 2 + m) * 16 + llo;
                pf[m] = *(const bf16x8*)(rQ + h * 8192 + t * 128 + ((ks * 64 + lhi * 16) ^ ((t & 7) << 4)));
            }
            #pragma unroll
            for (int n = 0; n < 2; ++n) {
                const int d = n * 16 + llo;
                const bf16x8 vf = *(const bf16x8*)(rA + h * 4096 + d * 128 + ((ks * 64 + lhi * 16) ^ ((d & 7) << 4)));
                #pragma unroll
                for (int m = 0; m < 2; ++m) pacc[m][n] = mfma16(pf[m], vf, pacc[m][n]);
            }
        }
    }
    __syncthreads();   // bar5: all VT/P reads done; rA free for AO
    {
        #pragma unroll
        for (int m = 0; m < 2; ++m) {
            #pragma unroll
            for (int n = 0; n < 2; ++n) {
                const int c = h * 32 + n * 16 + llo;
                #pragma unroll
                for (int r = 0; r < 4; ++r) {
                    const int i = (mh * 2 + m) * 16 + lhi * 4 + r;
                    *(unsigned short*)(rA + i * 384 + ((c * 2) ^ ((i & 7) << 4)))
                        = f2bf(pacc[m][n][r] * rinv[m][r]);
                }
            }
        }
    }
    __syncthreads();   // bar6: AO ready

    // ---------- Phase 4: proj GEMM + residual -> h written to out ----------
    {
        const int cbase = wave * 16;
        f32x4 acc[4] = {};
        #pragma unroll
        for (int ks = 0; ks < 6; ++ks) {
            bf16x8 af[4];
            const int kbyte = ks * 64 + lhi * 16;
            #pragma unroll
            for (int m = 0; m < 4; ++m) {
                const int row = m * 16 + llo;
                af[m] = *(const bf16x8*)(rA + row * 384 + (kbyte ^ ((row & 7) << 4)));
            }
            const int col = cbase + llo;
            const bf16x8 bfr = *(const bf16x8*)(projT + col * 192 + ks * 32 + lhi * 8);
            #pragma unroll
            for (int m = 0; m < 4; ++m) acc[m] = mfma16(af[m], bfr, acc[m]);
        }
        const int c = cbase + llo;
        const float pb = proj_b[c];
        #pragma unroll
        for (int m = 0; m < 4; ++m) {
            #pragma unroll
            for (int r = 0; r < 4; ++r) {
                const int i = m * 16 + lhi * 4 + r;
                const int base = sOpos[i];
                out[base + c] = x[base + c] + acc[m][r] + pb;
            }
        }
    }
    __syncthreads();   // bar7: h fully written (vmcnt drained before barrier); rA free

    // ---------- Phase 5: LN2 from out (L1/L2-hot) -> A2 in rA ----------
    if (tid < 512) {
        const int tok = tid >> 3;
        const int ch0 = (tid & 7) * 24;
        const float* hp = out + sOpos[tok];
        float v[24]; float s = 0.f, ss = 0.f;
        #pragma unroll
        for (int i = 0; i < 6; ++i) {
            const float4 f = *(const float4*)(hp + ch0 + i * 4);
            v[i*4]=f.x; v[i*4+1]=f.y; v[i*4+2]=f.z; v[i*4+3]=f.w;
            s += f.x + f.y + f.z + f.w;
            ss += f.x*f.x + f.y*f.y + f.z*f.z + f.w*f.w;
        }
        s  += __shfl_xor(s, 1);  s  += __shfl_xor(s, 2);  s  += __shfl_xor(s, 4);
        ss += __shfl_xor(ss, 1); ss += __shfl_xor(ss, 2); ss += __shfl_xor(ss, 4);
        const float mean = s * (1.f / 192.f);
        const float rstd = rsqrtf(ss * (1.f / 192.f) - mean * mean + 1e-5f);
        char* aBase = rA + tok * 384;
        const int sw = (tok & 7) << 4;
        #pragma unroll
        for (int i = 0; i < 12; ++i) {
            const int c = ch0 + i * 2;
            const float a0 = (v[i*2]   - mean) * rstd * n2g[c]   + n2b[c];
            const float a1 = (v[i*2+1] - mean) * rstd * n2g[c+1] + n2b[c+1];
            *(unsigned int*)(aBase + ((c * 2) ^ sw)) =
                (unsigned int)f2bf(a0) | ((unsigned int)f2bf(a1) << 16);
        }
    }
    __syncthreads();   // bar8: A2 ready (rQ/rK long dead -> G writable)

    // ---------- Phase 6: MLP GEMM1 (192->384) + exact GELU, wave -> cols [32w, 32w+32) ----------
    {
        const int cbase = wave * 32;
        f32x4 acc[4][2] = {};
        #pragma unroll
        for (int ks = 0; ks < 6; ++ks) {
            bf16x8 af[4];
            const int kbyte = ks * 64 + lhi * 16;
            #pragma unroll
            for (int m = 0; m < 4; ++m) {
                const int row = m * 16 + llo;
                af[m] = *(const bf16x8*)(rA + row * 384 + (kbyte ^ ((row & 7) << 4)));
            }
            #pragma unroll
            for (int n = 0; n < 2; ++n) {
                const int col = cbase + n * 16 + llo;
                const bf16x8 bfr = *(const bf16x8*)(w1T + col * 192 + ks * 32 + lhi * 8);
                #pragma unroll
                for (int m = 0; m < 4; ++m) acc[m][n] = mfma16(af[m], bfr, acc[m][n]);
            }
        }
        #pragma unroll
        for (int n = 0; n < 2; ++n) {
            const int c = cbase + n * 16 + llo;
            const float bb = b1[c];
            #pragma unroll
            for (int m = 0; m < 4; ++m) {
                #pragma unroll
                for (int r = 0; r < 4; ++r) {
                    const int i = m * 16 + lhi * 4 + r;
                    const float u = acc[m][n][r] + bb;
                    const float g = 0.5f * u * (1.f + erff(u * 0.70710678118654752f));
                    *(unsigned short*)(rG + i * 768 + ((c * 2) ^ ((i & 7) << 4))) = f2bf(g);
                }
            }
        }
    }
    __syncthreads();   // bar9: G ready

    // ---------- Phase 7: MLP GEMM2 (384->192) + final residual, wave -> cols [16w, 16w+16) ----------
    {
        const int cbase = wave * 16;
        f32x4 acc[4] = {};
        #pragma unroll
        for (int ks = 0; ks < 12; ++ks) {
            bf16x8 af[4];
            const int kbyte = ks * 64 + lhi * 16;
            #pragma unroll
            for (int m = 0; m < 4; ++m) {
                const int row = m * 16 + llo;
                af[m] = *(const bf16x8*)(rG + row * 768 + (kbyte ^ ((row & 7) << 4)));
            }
            const int col = cbase + llo;
            const bf16x8 bfr = *(const bf16x8*)(w2T + col * 384 + ks * 32 + lhi * 8);
            #pragma unroll
            for (int m = 0; m < 4; ++m) acc[m] = mfma16(af[m], bfr, acc[m]);
        }
        const int c = cbase + llo;
        const float bb = b2[c];
        #pragma unroll
        for (int m = 0; m < 4; ++m) {
            #pragma unroll
            for (int r = 0; r < 4; ++r) {
                const int i = m * 16 + lhi * 4 + r;
                float* p = out + sOpos[i] + c;
                *p = *p + acc[m][r] + bb;
            }
        }
    }
}

extern "C" void kernel_launch(void* const* d_in, const int* in_sizes, int n_in,
                              void* d_out, int out_size, void* d_ws, size_t ws_size,
                              hipStream_t stream)
{
    const float* x      = (const float*)d_in[0];
    const float* n1g    = (const float*)d_in[1];
    const float* n1b    = (const float*)d_in[2];
    const float* qkv_w  = (const float*)d_in[3];
    const float* qkv_b  = (const float*)d_in[4];
    const float* proj_w = (const float*)d_in[5];
    const float* proj_b = (const float*)d_in[6];
    const float* relTab = (const float*)d_in[7];
    const float* n2g    = (const float*)d_in[8];
    const float* n2b    = (const float*)d_in[9];
    const float* w1     = (const float*)d_in[10];
    const float* b1     = (const float*)d_in[11];
    const float* w2     = (const float*)d_in[12];
    const float* b2     = (const float*)d_in[13];
    float* out = (float*)d_out;

    char* ws = (char*)d_ws;
    unsigned short* qkvT  = (unsigned short*)(ws);            // [576][192] bf16
    unsigned short* projT = (unsigned short*)(ws + 221184);   // [192][192] bf16
    unsigned short* w1T   = (unsigned short*)(ws + 294912);   // [384][192] bf16
    unsigned short* w2T   = (unsigned short*)(ws + 442368);   // [192][384] bf16
    float*          biasT = (float*)(ws + 589824);            // [6][64][64] f32

    k_prep<<<1248, 256, 0, stream>>>(qkv_w, proj_w, w1, w2, relTab, qkvT, projT, w1T, w2T, biasT);
    k_fused<<<2048, 768, 0, stream>>>(x, n1g, n1b, qkvT, qkv_b, projT, proj_b, biasT,
                                      n2g, n2b, w1T, b1, w2T, b2, out);
}